// Round 7
// baseline (3550.542 us; speedup 1.0000x reference)
//
#include <hip/hip_runtime.h>
#include <math.h>

// Problem constants
#define B 32
#define SENC 64
#define SDEC 32
#define HDIM 512
#define EDIM 512
#define VDIM 32000
#define G4 2048              // 4*H
#define BH (B*HDIM)          // 16384
#define NBLK 256

// ---------------------------------------------------------------------------
// Coherent (cross-XCD) accessors. sc0 sc1 = system scope (bypasses L1+L2).
// Read-only weights use normal loads -> stay L2-cached.
// ---------------------------------------------------------------------------
__device__ __forceinline__ void agent_st(float* p, float v)
{
    __hip_atomic_store(p, v, __ATOMIC_RELAXED, __HIP_MEMORY_SCOPE_AGENT);
}
// Issue-only vector coherent load: caller MUST execute
// asm volatile("s_waitcnt vmcnt(0)" ::: "memory") before using the result.
__device__ __forceinline__ float4 agent_ld4(const float* p)
{
    float4 v;
    asm volatile("global_load_dwordx4 %0, %1, off sc0 sc1"
                 : "=v"(v) : "v"(p) : "memory");
    return v;
}
__device__ __forceinline__ void agent_stu(unsigned* p, unsigned v)
{
    asm volatile("global_store_dword %0, %1, off sc0 sc1"
                 :: "v"(p), "v"(v) : "memory");
}
__device__ __forceinline__ unsigned agent_ldu(const unsigned* p)
{
    unsigned v;
    asm volatile("global_load_dword %0, %1, off sc0 sc1"
                 : "=v"(v) : "v"(p) : "memory");
    asm volatile("s_waitcnt vmcnt(0)" ::: "memory");
    return v;
}

// ---------------------------------------------------------------------------
// Flag-based hierarchical grid barrier: NO atomics, no same-line RMW chains.
//  arrive:  each block stores its own padded flag line (parallel)
//  XCD master (blk<8): wave polls its 32 member flags (32 parallel loads)
//           -> stores xdone[xcd]
//  block 0: wave polls 8 xdone lines -> stores 8 per-XCD release lines
//  everyone: wave-coalesced read-only spin on own XCD's release line
// Monotonic epochs; vmcnt(0) drains coherent data stores before arrival.
// Layout (dword idx): blk flags at blk*16 (0..4095); xdone at 4096+x*16;
// release at 4224+x*16. One region per kernel instance.
// ---------------------------------------------------------------------------
#define BF_BLK(b)  ((b) << 4)
#define BF_XD(x)   (4096 + ((x) << 4))
#define BF_RL(x)   (4224 + ((x) << 4))

__device__ __forceinline__ void grid_barrier_f(unsigned* bar, int blk, int xcd,
                                               unsigned ep)
{
    asm volatile("s_waitcnt vmcnt(0) lgkmcnt(0)" ::: "memory");
    __syncthreads();
    int tid = threadIdx.x;
    if (tid < 64) {
        if (tid == 0) agent_stu(bar + BF_BLK(blk), ep);     // arrive
        if (blk < 8) {
            // XCD master (blk == xcd): poll the 32 member flags
            const unsigned* fp = bar + BF_BLK(xcd + ((tid & 31) << 3));
            for (;;) {
                unsigned v = agent_ldu(fp);
                if (__all(v >= ep)) break;
                __builtin_amdgcn_s_sleep(1);
            }
            if (tid == 0) agent_stu(bar + BF_XD(xcd), ep);
            if (blk == 0) {
                const unsigned* gp = bar + BF_XD(tid & 7);
                for (;;) {
                    unsigned v = agent_ldu(gp);
                    if (__all(v >= ep)) break;
                    __builtin_amdgcn_s_sleep(1);
                }
                if (tid < 8) agent_stu(bar + BF_RL(tid), ep);
            }
        }
        if (blk != 0) {
            const unsigned* rp = bar + BF_RL(xcd);
            for (;;) {
                unsigned v = agent_ldu(rp);      // same addr all lanes: 1 txn/wave
                if (__all(v >= ep)) break;
                __builtin_amdgcn_s_sleep(1);
            }
        }
    }
    __syncthreads();
}

// ---------------------------------------------------------------------------
// embed: gather emb rows for a token sequence  (n_tok blocks x 128 threads)
// ---------------------------------------------------------------------------
__global__ __launch_bounds__(128) void embed_kernel(const int* __restrict__ toks,
                                                    const float* __restrict__ emb,
                                                    float* __restrict__ out)
{
    int t = blockIdx.x;
    int id = toks[t];
    const float4* src = (const float4*)(emb + (size_t)id * EDIM);
    float4* dst = (float4*)(out + (size_t)t * EDIM);
    dst[threadIdx.x] = src[threadIdx.x];   // 128 * float4 = 512 floats
}

// ---------------------------------------------------------------------------
// NT SGEMM: C[m,n] = sum_k A[m*K+k]*B[n*ldb+k] (+bias0[n]+bias1[n])
// block tile 128x128, 256 threads, 8x8 microtile.
// ---------------------------------------------------------------------------
__global__ __launch_bounds__(256) void gemm_nt128(const float* __restrict__ A,
                                                  const float* __restrict__ Bm,
                                                  float* __restrict__ C,
                                                  const float* __restrict__ bias0,
                                                  const float* __restrict__ bias1,
                                                  int M, int N, int K, int ldb)
{
    __shared__ float As[16][128];
    __shared__ float Bs[16][128];
    int tid = threadIdx.x;
    int tx = tid & 15, ty = tid >> 4;            // 16 x 16 thread grid
    int m0 = blockIdx.y * 128, n0 = blockIdx.x * 128;

    float acc[8][8];
    #pragma unroll
    for (int i = 0; i < 8; i++)
        #pragma unroll
        for (int j = 0; j < 8; j++) acc[i][j] = 0.f;

    int lr = tid >> 1, lk = (tid & 1) * 8;       // row 0..127, k 0 or 8
    const float* Aptr = A + (size_t)(m0 + lr) * K + lk;
    const float* Bptr = Bm + (size_t)(n0 + lr) * ldb + lk;

    for (int k0 = 0; k0 < K; k0 += 16) {
        float4 a1 = *(const float4*)(Aptr + k0);
        float4 a2 = *(const float4*)(Aptr + k0 + 4);
        float4 b1 = *(const float4*)(Bptr + k0);
        float4 b2 = *(const float4*)(Bptr + k0 + 4);
        As[lk + 0][lr] = a1.x; As[lk + 1][lr] = a1.y;
        As[lk + 2][lr] = a1.z; As[lk + 3][lr] = a1.w;
        As[lk + 4][lr] = a2.x; As[lk + 5][lr] = a2.y;
        As[lk + 6][lr] = a2.z; As[lk + 7][lr] = a2.w;
        Bs[lk + 0][lr] = b1.x; Bs[lk + 1][lr] = b1.y;
        Bs[lk + 2][lr] = b1.z; Bs[lk + 3][lr] = b1.w;
        Bs[lk + 4][lr] = b2.x; Bs[lk + 5][lr] = b2.y;
        Bs[lk + 6][lr] = b2.z; Bs[lk + 7][lr] = b2.w;
        __syncthreads();
        #pragma unroll
        for (int kk = 0; kk < 16; kk++) {
            float4 av1 = *(const float4*)&As[kk][ty * 8];
            float4 av2 = *(const float4*)&As[kk][ty * 8 + 4];
            float4 bv1 = *(const float4*)&Bs[kk][tx * 8];
            float4 bv2 = *(const float4*)&Bs[kk][tx * 8 + 4];
            float am[8] = {av1.x, av1.y, av1.z, av1.w, av2.x, av2.y, av2.z, av2.w};
            float bn[8] = {bv1.x, bv1.y, bv1.z, bv1.w, bv2.x, bv2.y, bv2.z, bv2.w};
            #pragma unroll
            for (int i = 0; i < 8; i++)
                #pragma unroll
                for (int j = 0; j < 8; j++)
                    acc[i][j] += am[i] * bn[j];
        }
        __syncthreads();
    }

    int nc = n0 + tx * 8;
    float bb[8];
    #pragma unroll
    for (int j = 0; j < 8; j++) {
        bb[j] = 0.f;
        if (bias0) bb[j] += bias0[nc + j];
        if (bias1) bb[j] += bias1[nc + j];
    }
    #pragma unroll
    for (int i = 0; i < 8; i++) {
        int row = m0 + ty * 8 + i;
        float4 o1 = make_float4(acc[i][0] + bb[0], acc[i][1] + bb[1],
                                acc[i][2] + bb[2], acc[i][3] + bb[3]);
        float4 o2 = make_float4(acc[i][4] + bb[4], acc[i][5] + bb[5],
                                acc[i][6] + bb[6], acc[i][7] + bb[7]);
        *(float4*)(C + (size_t)row * N + nc) = o1;
        *(float4*)(C + (size_t)row * N + nc + 4) = o2;
    }
}

// ---------------------------------------------------------------------------
// NN SGEMM: C[m,n] = sum_k A[m*K+k]*B[k*N+n]  (for encT = enc_out @ attn_W)
// ---------------------------------------------------------------------------
__global__ __launch_bounds__(256) void gemm_nn128(const float* __restrict__ A,
                                                  const float* __restrict__ Bm,
                                                  float* __restrict__ C,
                                                  int M, int N, int K)
{
    __shared__ float As[16][128];
    __shared__ float Bs[16][128];
    int tid = threadIdx.x;
    int tx = tid & 15, ty = tid >> 4;
    int m0 = blockIdx.y * 128, n0 = blockIdx.x * 128;

    float acc[8][8];
    #pragma unroll
    for (int i = 0; i < 8; i++)
        #pragma unroll
        for (int j = 0; j < 8; j++) acc[i][j] = 0.f;

    int lr = tid >> 1, lk = (tid & 1) * 8;
    const float* Aptr = A + (size_t)(m0 + lr) * K + lk;
    int bk = tid >> 5;                // 0..7
    int bn = (tid & 31) << 2;         // 0..124

    for (int k0 = 0; k0 < K; k0 += 16) {
        float4 a1 = *(const float4*)(Aptr + k0);
        float4 a2 = *(const float4*)(Aptr + k0 + 4);
        float4 v1 = *(const float4*)(Bm + (size_t)(k0 + bk) * N + n0 + bn);
        float4 v2 = *(const float4*)(Bm + (size_t)(k0 + bk + 8) * N + n0 + bn);
        As[lk + 0][lr] = a1.x; As[lk + 1][lr] = a1.y;
        As[lk + 2][lr] = a1.z; As[lk + 3][lr] = a1.w;
        As[lk + 4][lr] = a2.x; As[lk + 5][lr] = a2.y;
        As[lk + 6][lr] = a2.z; As[lk + 7][lr] = a2.w;
        *(float4*)&Bs[bk][bn] = v1;
        *(float4*)&Bs[bk + 8][bn] = v2;
        __syncthreads();
        #pragma unroll
        for (int kk = 0; kk < 16; kk++) {
            float4 av1 = *(const float4*)&As[kk][ty * 8];
            float4 av2 = *(const float4*)&As[kk][ty * 8 + 4];
            float4 bv1 = *(const float4*)&Bs[kk][tx * 8];
            float4 bv2 = *(const float4*)&Bs[kk][tx * 8 + 4];
            float am[8] = {av1.x, av1.y, av1.z, av1.w, av2.x, av2.y, av2.z, av2.w};
            float bv[8] = {bv1.x, bv1.y, bv1.z, bv1.w, bv2.x, bv2.y, bv2.z, bv2.w};
            #pragma unroll
            for (int i = 0; i < 8; i++)
                #pragma unroll
                for (int j = 0; j < 8; j++)
                    acc[i][j] += am[i] * bv[j];
        }
        __syncthreads();
    }

    int nc = n0 + tx * 8;
    #pragma unroll
    for (int i = 0; i < 8; i++) {
        int row = m0 + ty * 8 + i;
        float4 o1 = make_float4(acc[i][0], acc[i][1], acc[i][2], acc[i][3]);
        float4 o2 = make_float4(acc[i][4], acc[i][5], acc[i][6], acc[i][7]);
        *(float4*)(C + (size_t)row * N + nc) = o1;
        *(float4*)(C + (size_t)row * N + nc + 4) = o2;
    }
}

// ---------------------------------------------------------------------------
// helpers
// ---------------------------------------------------------------------------
__device__ __forceinline__ float allreduce64(float v)
{
    #pragma unroll
    for (int m = 1; m < 64; m <<= 1) v += __shfl_xor(v, m);
    return v;
}

__device__ __forceinline__ float2 lstm_update(float i_, float f_, float g_,
                                              float o_, float c)
{
    float ig = 1.f / (1.f + expf(-i_));
    float fg = 1.f / (1.f + expf(-f_));
    float gg = tanhf(g_);
    float og = 1.f / (1.f + expf(-o_));
    float cn = fg * c + ig * gg;
    float hn = og * tanhf(cn);
    return make_float2(hn, cn);
}

// ---------------------------------------------------------------------------
// Fused 2-layer encoder as a time-pipeline. 65 macro-steps, 1 barrier each.
// Blocks: xcd = blk&7, slot = blk>>3. role = slot>>4 (0: layer0, 1: layer1).
// s2 = slot&15: jgroup = xcd*8 + (s2>>1) (weights XCD-pinned), bg2 = s2&1
// (16 batch rows per block; thread handles b and b+8).
// Layer0 at step u computes t=u using precomputed xg; layer1 at u computes
// t=u-1 with Wih1@h0(t) + Whh1@h1(t-1) on the fly (no pre-gate GEMM).
// c state in registers of tid<128; h exchanged via coherent parity buffers.
// ---------------------------------------------------------------------------
__global__ __launch_bounds__(256) void enc_fused(
    const float* __restrict__ xg, const float* __restrict__ Whh0,
    const float* __restrict__ Wih1, const float* __restrict__ Whh1,
    const float* __restrict__ bih1, const float* __restrict__ bhh1,
    float* __restrict__ l1out, float* __restrict__ h0buf,
    float* __restrict__ h1buf, float* __restrict__ hT, float* __restrict__ cT,
    unsigned* __restrict__ bar)
{
    __shared__ __align__(16) float hs[16][520];
    __shared__ __align__(16) float is_[16][520];
    __shared__ float gacc[8][16][5];
    int blk = blockIdx.x;
    int xcd = blk & 7, slot = blk >> 3;
    int role = slot >> 4;
    int s2 = slot & 15;
    int jgroup = xcd * 8 + (s2 >> 1);        // [0,64)
    int bg2 = s2 & 1;
    int tid = threadIdx.x;
    int r = tid >> 3, bb = tid & 7;
    int g = r >> 3, jj = r & 7;
    int row = (g << 9) + (jgroup << 3) + jj; // gate-row in [0,2048)
    int b0 = (bg2 << 4) + bb;
    const float* w0 = role ? (Wih1 + (size_t)row * 512)
                           : (Whh0 + (size_t)row * 512);
    const float* w1 = role ? (Whh1 + (size_t)row * 512) : (const float*)0;
    float bsum = role ? (bih1[row] + bhh1[row]) : 0.f;
    float creg = 0.f;
    unsigned ep = 0;
    int p = 0;
    for (int u = 0; u <= SENC; ++u) {
        int active = role ? (u >= 1) : (u < SENC);
        int t = role ? (u - 1) : u;
        if (active) {
            // ---- stage inputs into LDS ----
            if (!role) {
                if (t == 0) {
                    float4 z = make_float4(0.f, 0.f, 0.f, 0.f);
                    #pragma unroll
                    for (int v = 0; v < 8; v++) {
                        int d = (tid + (v << 8)) << 2;
                        *(float4*)&hs[d >> 9][d & 511] = z;
                    }
                } else {
                    const float4* s4 = (const float4*)(h0buf + p * BH + ((bg2 << 4) << 9));
                    float4 hv[8];
                    #pragma unroll
                    for (int v = 0; v < 8; v++)
                        hv[v] = agent_ld4((const float*)(s4 + tid + (v << 8)));
                    asm volatile("s_waitcnt vmcnt(0)" ::: "memory");
                    #pragma unroll
                    for (int v = 0; v < 8; v++) {
                        int d = (tid + (v << 8)) << 2;
                        *(float4*)&hs[d >> 9][d & 511] = hv[v];
                    }
                }
            } else {
                const float4* s40 = (const float4*)(h0buf + p * BH + ((bg2 << 4) << 9));
                float4 hv[8];
                #pragma unroll
                for (int v = 0; v < 8; v++)
                    hv[v] = agent_ld4((const float*)(s40 + tid + (v << 8)));
                if (t == 0) {
                    asm volatile("s_waitcnt vmcnt(0)" ::: "memory");
                    float4 z = make_float4(0.f, 0.f, 0.f, 0.f);
                    #pragma unroll
                    for (int v = 0; v < 8; v++) {
                        int d = (tid + (v << 8)) << 2;
                        *(float4*)&hs[d >> 9][d & 511] = hv[v];
                        *(float4*)&is_[d >> 9][d & 511] = z;
                    }
                } else {
                    const float4* s41 = (const float4*)(h1buf + p * BH + ((bg2 << 4) << 9));
                    float4 iv[8];
                    #pragma unroll
                    for (int v = 0; v < 8; v++)
                        iv[v] = agent_ld4((const float*)(s41 + tid + (v << 8)));
                    asm volatile("s_waitcnt vmcnt(0)" ::: "memory");
                    #pragma unroll
                    for (int v = 0; v < 8; v++) {
                        int d = (tid + (v << 8)) << 2;
                        *(float4*)&hs[d >> 9][d & 511] = hv[v];
                        *(float4*)&is_[d >> 9][d & 511] = iv[v];
                    }
                }
            }
            __syncthreads();
            // ---- gates for (b0) and (b0+8) ----
            float acc0, acc1;
            if (!role) {
                acc0 = xg[(size_t)(b0 * SENC + t) * G4 + row];
                acc1 = xg[(size_t)((b0 + 8) * SENC + t) * G4 + row];
                float a00 = 0, a01 = 0, a02 = 0, a03 = 0;
                float a10 = 0, a11 = 0, a12 = 0, a13 = 0;
                const float* ha = hs[bb];
                const float* hb = hs[bb + 8];
                #pragma unroll 4
                for (int k = 0; k < 512; k += 4) {
                    float4 w = *(const float4*)(w0 + k);
                    float4 x = *(const float4*)(ha + k);
                    float4 y = *(const float4*)(hb + k);
                    a00 += w.x * x.x; a01 += w.y * x.y;
                    a02 += w.z * x.z; a03 += w.w * x.w;
                    a10 += w.x * y.x; a11 += w.y * y.y;
                    a12 += w.z * y.z; a13 += w.w * y.w;
                }
                acc0 += (a00 + a01) + (a02 + a03);
                acc1 += (a10 + a11) + (a12 + a13);
            } else {
                float a00 = 0, a01 = 0, a02 = 0, a03 = 0;
                float a10 = 0, a11 = 0, a12 = 0, a13 = 0;
                const float* h0a = hs[bb];
                const float* h0b = hs[bb + 8];
                const float* h1a = is_[bb];
                const float* h1b = is_[bb + 8];
                #pragma unroll 2
                for (int k = 0; k < 512; k += 4) {
                    float4 wi = *(const float4*)(w0 + k);
                    float4 wh = *(const float4*)(w1 + k);
                    float4 xa = *(const float4*)(h0a + k);
                    float4 xb = *(const float4*)(h0b + k);
                    float4 ya = *(const float4*)(h1a + k);
                    float4 yb = *(const float4*)(h1b + k);
                    a00 += wi.x * xa.x + wh.x * ya.x;
                    a01 += wi.y * xa.y + wh.y * ya.y;
                    a02 += wi.z * xa.z + wh.z * ya.z;
                    a03 += wi.w * xa.w + wh.w * ya.w;
                    a10 += wi.x * xb.x + wh.x * yb.x;
                    a11 += wi.y * xb.y + wh.y * yb.y;
                    a12 += wi.z * xb.z + wh.z * yb.z;
                    a13 += wi.w * xb.w + wh.w * yb.w;
                }
                acc0 = bsum + (a00 + a01) + (a02 + a03);
                acc1 = bsum + (a10 + a11) + (a12 + a13);
            }
            gacc[jj][bb][g] = acc0;
            gacc[jj][bb + 8][g] = acc1;
            __syncthreads();
            // ---- LSTM update (tid<128: one (b,jh) cell each) ----
            if (tid < 128) {
                int ujj = tid & 7, ulb = tid >> 3;    // ulb 0..15
                float g0 = gacc[ujj][ulb][0], g1 = gacc[ujj][ulb][1];
                float g2 = gacc[ujj][ulb][2], g3 = gacc[ujj][ulb][3];
                float2 hc = lstm_update(g0, g1, g2, g3, creg);
                creg = hc.y;
                int ub = (bg2 << 4) + ulb;
                int ujh = (jgroup << 3) + ujj;
                if (!role) {
                    agent_st(h0buf + (p ^ 1) * BH + ub * 512 + ujh, hc.x);
                    if (t == SENC - 1) {
                        hT[ub * 512 + ujh] = hc.x;
                        cT[ub * 512 + ujh] = hc.y;
                    }
                } else {
                    agent_st(h1buf + (p ^ 1) * BH + ub * 512 + ujh, hc.x);
                    l1out[(size_t)(ub * SENC + t) * 512 + ujh] = hc.x;
                    if (t == SENC - 1) {
                        hT[BH + ub * 512 + ujh] = hc.x;
                        cT[BH + ub * 512 + ujh] = hc.y;
                    }
                }
            }
        }
        ep++;
        grid_barrier_f(bar, blk, xcd, ep);
        p ^= 1;
    }
}

// ---------------------------------------------------------------------------
// Decoder LSTM cell phase (device fn). Coherent x4 staging; L2 weights.
// ---------------------------------------------------------------------------
__device__ __forceinline__ void cell_phase(
    const float* __restrict__ Wih, const float* __restrict__ Whh,
    float bsum,
    const float* __restrict__ inp, const float* __restrict__ h_in,
    float* __restrict__ h_out, float* __restrict__ seqout,
    float& creg, int t, int jg, int bg, int row,
    float (*hs)[520], float (*is_)[520], float (*gacc)[8][5])
{
    int tid = threadIdx.x;
    {
        const float4* hsrc4 = (const float4*)(h_in + ((bg << 3) << 9));
        const float4* isrc4 = (const float4*)(inp + ((bg << 3) << 9));
        float4 hv4[4], iv4[4];
        #pragma unroll
        for (int u = 0; u < 4; u++) {
            hv4[u] = agent_ld4((const float*)(hsrc4 + tid + (u << 8)));
            iv4[u] = agent_ld4((const float*)(isrc4 + tid + (u << 8)));
        }
        asm volatile("s_waitcnt vmcnt(0)" ::: "memory");
        #pragma unroll
        for (int u = 0; u < 4; u++) {
            int d = (tid + (u << 8)) << 2;
            int rb = d >> 9, kk = d & 511;
            *(float4*)&hs[rb][kk] = hv4[u];
            *(float4*)&is_[rb][kk] = iv4[u];
        }
    }
    __syncthreads();
    int r = tid >> 3, bb = tid & 7;
    int g = r >> 3, jj = r & 7;
    const float* wi = Wih + (size_t)row * 512;
    const float* wh = Whh + (size_t)row * 512;
    const float* ir = is_[bb];
    const float* hr = hs[bb];
    float a0 = 0.f, a1 = 0.f, a2 = 0.f, a3 = 0.f;
    #pragma unroll 8
    for (int k = 0; k < 512; k += 4) {
        float4 wiv = *(const float4*)(wi + k);
        float4 iv = *(const float4*)(ir + k);
        float4 whv = *(const float4*)(wh + k);
        float4 hv = *(const float4*)(hr + k);
        a0 += wiv.x * iv.x + whv.x * hv.x;
        a1 += wiv.y * iv.y + whv.y * hv.y;
        a2 += wiv.z * iv.z + whv.z * hv.z;
        a3 += wiv.w * iv.w + whv.w * hv.w;
    }
    gacc[jj][bb][g] = bsum + (a0 + a1) + (a2 + a3);
    __syncthreads();
    if (tid < 64) {
        int ujj = tid & 7, ubb = tid >> 3;
        float g0 = gacc[ujj][ubb][0], g1 = gacc[ujj][ubb][1];
        float g2 = gacc[ujj][ubb][2], g3 = gacc[ujj][ubb][3];
        float2 hc = lstm_update(g0, g1, g2, g3, creg);
        creg = hc.y;
        int ub = (bg << 3) + ubb, ujh = (jg << 3) + ujj;
        agent_st(h_out + ub * 512 + ujh, hc.x);
        if (seqout) seqout[(size_t)(ub * SDEC + t) * 512 + ujh] = hc.x;
    }
}

// ---------------------------------------------------------------------------
// Persistent decoder: 32 timesteps x 3 barriers (minimum for the serial
// chain attn -> cell0 -> cell1).
// Phase A (all 256 blocks): ab = xcd*4+(slot>>3), e0 = (slot&7)*64.
//   pw[s] = h2 . encT[ab,s] (attn_W pre-applied), softmax (redundant per-b
//   across the 8 e-slice blocks, deterministic), then
//   inp[ab,e0+e] = tanh(yg[ab,t,e0+e] + sum_s aw[s]*encC[ab,s,e0+e])
//   with encC = enc_out @ comb_W[:,512:]^T precomputed -> the decoder never
//   touches enc_out or comb_W (keeps per-XCD L2 set ~3.3 MB < 4 MiB).
// Phases B/C: LSTM cells, weight rows XCD-pinned.
// ---------------------------------------------------------------------------
__global__ __launch_bounds__(256) void decoder_persist(
    const int* __restrict__ xs,
    const float* __restrict__ encT, const float* __restrict__ encC,
    const float* __restrict__ yg,
    const float* __restrict__ Wih0, const float* __restrict__ Whh0,
    const float* __restrict__ bih0, const float* __restrict__ bhh0,
    const float* __restrict__ Wih1, const float* __restrict__ Whh1,
    const float* __restrict__ bih1, const float* __restrict__ bhh1,
    const float* __restrict__ hT0, const float* __restrict__ cT0,
    const float* __restrict__ hT1, const float* __restrict__ cT1,
    float* __restrict__ dhb0, float* __restrict__ dhb1,
    float* __restrict__ inpbuf, float* __restrict__ h2seq,
    unsigned* __restrict__ bar)
{
    __shared__ __align__(16) float hs[8][520];
    __shared__ __align__(16) float is_[8][520];
    __shared__ float gacc[8][8][5];
    __shared__ __align__(16) float h2s[512];
    __shared__ float psum[4][64];
    __shared__ float pw[64];
    __shared__ float aw[64];
    int blk = blockIdx.x;
    int xcd = blk & 7, slot = blk >> 3;
    int jg = xcd * 8 + (slot >> 2), bg = slot & 3;    // cell role
    int ab = xcd * 4 + (slot >> 3);                   // attention b (XCD-pinned)
    int e0 = (slot & 7) << 6;                         // attention e-slice
    int tid = threadIdx.x;
    int lane = tid & 63, wv = tid >> 6;
    int r = tid >> 3;
    int g = r >> 3, jj = r & 7;
    int row = (g << 9) + (jg << 3) + jj;
    float bsum0 = bih0[row] + bhh0[row];
    float bsum1 = bih1[row] + bhh1[row];
    float c0 = 0.f, c1 = 0.f;
    if (tid < 64) {
        int ujj = tid & 7, ubb = tid >> 3;
        int ub = (bg << 3) + ubb, ujh = (jg << 3) + ujj;
        c0 = cT0[ub * 512 + ujh];
        c1 = cT1[ub * 512 + ujh];
    }
    unsigned ep = 0;
    int p = 0;
    for (int t = 0; t < SDEC; ++t) {
        int q = p ^ 1;
        // ---- Phase A: attention + combine ----
        {
            const float* h2p = ((t == 0) ? hT1 : dhb1 + p * BH) + ab * 512;
            if (tid < 128) {
                float4 v = agent_ld4((const float*)((const float4*)h2p + tid));
                asm volatile("s_waitcnt vmcnt(0)" ::: "memory");
                ((float4*)h2s)[tid] = v;
            }
            __syncthreads();
            // pw[s] = h2 . encT[ab,s] - neg (redundant across e-slice blocks)
            for (int s = wv; s < SENC; s += 4) {
                const float* rowp = encT + (size_t)(ab * SENC + s) * 512;
                float pp = 0.f;
                #pragma unroll
                for (int i = 0; i < 8; i++)
                    pp += h2s[lane + 64 * i] * rowp[lane + 64 * i];
                pp = allreduce64(pp);
                if (lane == 0)
                    pw[s] = pp - ((xs[ab * SENC + s] > 0) ? 0.f : 1e20f);
            }
            __syncthreads();
            if (tid < 64) {
                float v = pw[tid];
                float m = v;
                #pragma unroll
                for (int o = 1; o < 64; o <<= 1) m = fmaxf(m, __shfl_xor(m, o));
                float ex = expf(v - m);
                float sm = ex;
                #pragma unroll
                for (int o = 1; o < 64; o <<= 1) sm += __shfl_xor(sm, o);
                aw[tid] = ex / sm;
            }
            __syncthreads();
            // inp[e0+lane] = tanh(yg + sum_s aw[s]*encC[ab,s,e0+lane])
            // wave wv sums s in [wv*16, wv*16+16), coalesced 256B rows
            {
                float part = 0.f;
                const float* cb = encC + (size_t)(ab * SENC + (wv << 4)) * 512
                                + e0 + lane;
                #pragma unroll
                for (int si = 0; si < 16; si++)
                    part += aw[(wv << 4) + si] * cb[si * 512];
                psum[wv][lane] = part;
            }
            __syncthreads();
            if (tid < 64) {
                float v = psum[0][tid] + psum[1][tid] + psum[2][tid] + psum[3][tid];
                float rr = tanhf(yg[(size_t)(ab * SDEC + t) * 512 + e0 + tid] + v);
                agent_st(inpbuf + ab * 512 + e0 + tid, rr);
            }
        }
        ep++; grid_barrier_f(bar, blk, xcd, ep);
        // ---- Phase B: layer-0 cell ----
        cell_phase(Wih0, Whh0, bsum0, inpbuf,
                   (t == 0) ? hT0 : dhb0 + p * BH, dhb0 + q * BH,
                   (float*)nullptr, c0, t, jg, bg, row, hs, is_, gacc);
        ep++; grid_barrier_f(bar, blk, xcd, ep);
        // ---- Phase C: layer-1 cell ----
        cell_phase(Wih1, Whh1, bsum1, dhb0 + q * BH,
                   (t == 0) ? hT1 : dhb1 + p * BH, dhb1 + q * BH,
                   h2seq, c1, t, jg, bg, row, hs, is_, gacc);
        ep++; grid_barrier_f(bar, blk, xcd, ep);
        p = q;
    }
}

// ---------------------------------------------------------------------------
// argmax over scores[m, 1:], lowest index on ties; preds[m] = index (float)
// ---------------------------------------------------------------------------
__global__ __launch_bounds__(256) void argmax_kernel(const float* __restrict__ scores,
                                                     float* __restrict__ preds)
{
    __shared__ float sv[256];
    __shared__ int si[256];
    int m = blockIdx.x;
    const float* row = scores + (size_t)m * VDIM;
    float best = -3.4e38f;
    int bi = 0x7fffffff;
    for (int v = 1 + (int)threadIdx.x; v < VDIM; v += 256) {
        float val = row[v];
        if (val > best) { best = val; bi = v; }   // ascending scan → lowest idx kept
    }
    sv[threadIdx.x] = best;
    si[threadIdx.x] = bi;
    __syncthreads();
    for (int s = 128; s > 0; s >>= 1) {
        if ((int)threadIdx.x < s) {
            float ov = sv[threadIdx.x + s];
            int oi = si[threadIdx.x + s];
            if (ov > sv[threadIdx.x] ||
                (ov == sv[threadIdx.x] && oi < si[threadIdx.x])) {
                sv[threadIdx.x] = ov;
                si[threadIdx.x] = oi;
            }
        }
        __syncthreads();
    }
    if (threadIdx.x == 0) preds[m] = (float)si[0];
}

// ---------------------------------------------------------------------------
extern "C" void kernel_launch(void* const* d_in, const int* in_sizes, int n_in,
                              void* d_out, int out_size, void* d_ws, size_t ws_size,
                              hipStream_t stream)
{
    const int* xs = (const int*)d_in[0];
    const int* ys = (const int*)d_in[1];
    const float* emb = (const float*)d_in[2];
    const float* W[16];
    for (int i = 0; i < 16; i++) W[i] = (const float*)d_in[3 + i];
    // enc layer l: W[l*4+{0:Wih,1:Whh,2:bih,3:bhh}] ; dec layer l: W[8+l*4+...]
    const float* attn_W = (const float*)d_in[19];
    const float* comb_W = (const float*)d_in[20];
    float* out = (float*)d_out;
    float* ws = (float*)d_ws;

    // workspace layout (floats)
    float* xemb   = ws;                    // 2048*512
    float* xg     = xemb + 1048576;        // 2048*2048 (layer-0 pre-gates)
    float* l1out  = xg + 4194304;          // 2048*512  (enc_out)
    float* encT   = l1out + 1048576;       // 2048*512  (enc_out @ attn_W)
    float* h0buf  = encT + 1048576;        // 2*BH
    float* h1buf  = h0buf + 2 * BH;        // 2*BH
    float* hT     = h1buf + 2 * BH;        // 2*BH (layer0 | layer1)
    float* cT     = hT + 2 * BH;           // 2*BH
    unsigned* barcnt = (unsigned*)(cT + 2 * BH);   // 2 x 8192 dwords (flag barrier)
    // ys embeddings overlay xemb (dead after layer-0 pre-gate GEMM)
    float* yemb   = xemb;                  // 1024*512
    // decoder buffers overlay xg (dead after encoder)
    float* h2seq  = xg;                    // 1024*512
    float* inpbuf = xg + 524288;           // BH
    float* dhb0   = inpbuf + BH;           // 2*BH parity
    float* dhb1   = dhb0 + 2 * BH;         // 2*BH parity
    float* yg     = dhb1 + 2 * BH;         // 1024*512 (yemb @ Wxe^T)
    float* encC   = yg + 524288;           // 2048*512 (enc_out @ Wc^T)

    hipMemsetAsync(barcnt, 0, 2 * 8192 * 4, stream);

    // ---- Encoder ----
    embed_kernel<<<B * SENC, 128, 0, stream>>>(xs, emb, xemb);
    gemm_nt128<<<dim3(G4 / 128, (B * SENC) / 128), 256, 0, stream>>>(
        xemb, W[0], xg, W[2], W[3], B * SENC, G4, 512, 512);
    embed_kernel<<<B * SDEC, 128, 0, stream>>>(ys, emb, yemb);
    {
        const float* xgp = xg;
        const float* whh0 = W[1];
        const float* wih1 = W[4];
        const float* whh1 = W[5];
        const float* bih1 = W[6];
        const float* bhh1 = W[7];
        float* l1o = l1out;
        float* h0b = h0buf;
        float* h1b = h1buf;
        float* hTp = hT;
        float* cTp = cT;
        unsigned* bp = barcnt;
        void* eargs[] = {(void*)&xgp, (void*)&whh0, (void*)&wih1, (void*)&whh1,
                         (void*)&bih1, (void*)&bhh1, (void*)&l1o, (void*)&h0b,
                         (void*)&h1b, (void*)&hTp, (void*)&cTp, (void*)&bp};
        hipLaunchCooperativeKernel((void*)enc_fused, dim3(NBLK), dim3(256),
                                   eargs, 0, stream);
    }

    // ---- Attention precomputes (off the recurrence) ----
    gemm_nn128<<<dim3(512 / 128, (B * SENC) / 128), 256, 0, stream>>>(
        l1out, attn_W, encT, B * SENC, 512, 512);
    gemm_nt128<<<dim3(512 / 128, (B * SDEC) / 128), 256, 0, stream>>>(
        yemb, comb_W, yg, nullptr, nullptr, B * SDEC, 512, 512, 1024);
    gemm_nt128<<<dim3(512 / 128, (B * SENC) / 128), 256, 0, stream>>>(
        l1out, comb_W + 512, encC, nullptr, nullptr, B * SENC, 512, 512, 1024);

    // ---- Decoder (single persistent kernel, 3 barriers/step) ----
    {
        const int* xs_ = xs;
        const float* encT_ = encT;
        const float* encC_ = encC;
        const float* yg_ = yg;
        const float* wih0 = W[8];
        const float* whh0 = W[9];
        const float* bih0 = W[10];
        const float* bhh0 = W[11];
        const float* wih1 = W[12];
        const float* whh1 = W[13];
        const float* bih1 = W[14];
        const float* bhh1 = W[15];
        const float* hT0_ = hT;
        const float* cT0_ = cT;
        const float* hT1_ = hT + BH;
        const float* cT1_ = cT + BH;
        float* dhb0_ = dhb0;
        float* dhb1_ = dhb1;
        float* inp_ = inpbuf;
        float* h2seq_ = h2seq;
        unsigned* bp = barcnt + 8192;
        void* dargs[] = {(void*)&xs_, (void*)&encT_, (void*)&encC_,
                         (void*)&yg_,
                         (void*)&wih0, (void*)&whh0, (void*)&bih0, (void*)&bhh0,
                         (void*)&wih1, (void*)&whh1, (void*)&bih1, (void*)&bhh1,
                         (void*)&hT0_, (void*)&cT0_, (void*)&hT1_, (void*)&cT1_,
                         (void*)&dhb0_, (void*)&dhb1_, (void*)&inp_, (void*)&h2seq_,
                         (void*)&bp};
        hipLaunchCooperativeKernel((void*)decoder_persist, dim3(NBLK), dim3(256),
                                   dargs, 0, stream);
    }

    // ---- Output projection + argmax ----
    gemm_nt128<<<dim3(VDIM / 128, (B * SDEC) / 128), 256, 0, stream>>>(
        h2seq, emb, out + B * SDEC, nullptr, nullptr, B * SDEC, VDIM, 512, 512);
    argmax_kernel<<<B * SDEC, 256, 0, stream>>>(out + B * SDEC, out);
}

// Round 8
// 3151.720 us; speedup vs baseline: 1.1265x; 1.1265x over previous
//
#include <hip/hip_runtime.h>
#include <math.h>

// Problem constants
#define B 32
#define SENC 64
#define SDEC 32
#define HDIM 512
#define EDIM 512
#define VDIM 32000
#define G4 2048              // 4*H
#define BH (B*HDIM)          // 16384
#define NBLK 256

// ---------------------------------------------------------------------------
// Coherent (cross-XCD) accessors. sc0 sc1 = system scope (bypasses L1+L2).
// Read-only weights use normal loads -> stay L2-cached.
// ---------------------------------------------------------------------------
__device__ __forceinline__ void agent_st(float* p, float v)
{
    __hip_atomic_store(p, v, __ATOMIC_RELAXED, __HIP_MEMORY_SCOPE_AGENT);
}
// Issue-only vector coherent load: caller MUST execute
// asm volatile("s_waitcnt vmcnt(0)" ::: "memory") before using the result.
__device__ __forceinline__ float4 agent_ld4(const float* p)
{
    float4 v;
    asm volatile("global_load_dwordx4 %0, %1, off sc0 sc1"
                 : "=v"(v) : "v"(p) : "memory");
    return v;
}
__device__ __forceinline__ void agent_stu(unsigned* p, unsigned v)
{
    asm volatile("global_store_dword %0, %1, off sc0 sc1"
                 :: "v"(p), "v"(v) : "memory");
}
__device__ __forceinline__ unsigned agent_ldu(const unsigned* p)
{
    unsigned v;
    asm volatile("global_load_dword %0, %1, off sc0 sc1"
                 : "=v"(v) : "v"(p) : "memory");
    asm volatile("s_waitcnt vmcnt(0)" ::: "memory");
    return v;
}

// ---------------------------------------------------------------------------
// Dataflow sync primitives (no grid barriers).
// pollge: the calling WAVE (all active lanes, one flag line per lane) spins
// until every polled flag >= ep. Flag lines are 64 B apart.
// flag_release: drain this block's coherent data stores, then lane 0
// publishes the epoch flag.
// ---------------------------------------------------------------------------
__device__ __forceinline__ void pollge(const unsigned* p, unsigned ep)
{
    for (;;) {
        unsigned v = agent_ldu(p);
        if (__all(v >= ep)) break;
        __builtin_amdgcn_s_sleep(1);
    }
}

__device__ __forceinline__ void flag_release(unsigned* line, unsigned ep)
{
    asm volatile("s_waitcnt vmcnt(0) lgkmcnt(0)" ::: "memory");
    __syncthreads();
    if (threadIdx.x == 0) agent_stu(line, ep);
}

// Flag regions (dword offsets into flg; one 16-dword line per producer):
//  enc F0 : 0     + (jgroup*2+bg2)*16      (128 lines)
//  enc F1 : 2048  + (jgroup*2+bg2)*16      (128 lines)
//  dec FA : 4096  + (ab*8+esl)*16          (256 lines)
//  dec FB : 8192  + (jg*4+bg)*16           (256 lines)
//  dec FC : 12288 + (jg*4+bg)*16           (256 lines)
#define FLG_BYTES 65536

// ---------------------------------------------------------------------------
// embed: gather emb rows for a token sequence  (n_tok blocks x 128 threads)
// ---------------------------------------------------------------------------
__global__ __launch_bounds__(128) void embed_kernel(const int* __restrict__ toks,
                                                    const float* __restrict__ emb,
                                                    float* __restrict__ out)
{
    int t = blockIdx.x;
    int id = toks[t];
    const float4* src = (const float4*)(emb + (size_t)id * EDIM);
    float4* dst = (float4*)(out + (size_t)t * EDIM);
    dst[threadIdx.x] = src[threadIdx.x];   // 128 * float4 = 512 floats
}

// ---------------------------------------------------------------------------
// NT SGEMM: C[m,n] = sum_k A[m*K+k]*B[n*ldb+k] (+bias0[n]+bias1[n])
// block tile 128x128, 256 threads, 8x8 microtile.
// ---------------------------------------------------------------------------
__global__ __launch_bounds__(256) void gemm_nt128(const float* __restrict__ A,
                                                  const float* __restrict__ Bm,
                                                  float* __restrict__ C,
                                                  const float* __restrict__ bias0,
                                                  const float* __restrict__ bias1,
                                                  int M, int N, int K, int ldb)
{
    __shared__ float As[16][128];
    __shared__ float Bs[16][128];
    int tid = threadIdx.x;
    int tx = tid & 15, ty = tid >> 4;            // 16 x 16 thread grid
    int m0 = blockIdx.y * 128, n0 = blockIdx.x * 128;

    float acc[8][8];
    #pragma unroll
    for (int i = 0; i < 8; i++)
        #pragma unroll
        for (int j = 0; j < 8; j++) acc[i][j] = 0.f;

    int lr = tid >> 1, lk = (tid & 1) * 8;       // row 0..127, k 0 or 8
    const float* Aptr = A + (size_t)(m0 + lr) * K + lk;
    const float* Bptr = Bm + (size_t)(n0 + lr) * ldb + lk;

    for (int k0 = 0; k0 < K; k0 += 16) {
        float4 a1 = *(const float4*)(Aptr + k0);
        float4 a2 = *(const float4*)(Aptr + k0 + 4);
        float4 b1 = *(const float4*)(Bptr + k0);
        float4 b2 = *(const float4*)(Bptr + k0 + 4);
        As[lk + 0][lr] = a1.x; As[lk + 1][lr] = a1.y;
        As[lk + 2][lr] = a1.z; As[lk + 3][lr] = a1.w;
        As[lk + 4][lr] = a2.x; As[lk + 5][lr] = a2.y;
        As[lk + 6][lr] = a2.z; As[lk + 7][lr] = a2.w;
        Bs[lk + 0][lr] = b1.x; Bs[lk + 1][lr] = b1.y;
        Bs[lk + 2][lr] = b1.z; Bs[lk + 3][lr] = b1.w;
        Bs[lk + 4][lr] = b2.x; Bs[lk + 5][lr] = b2.y;
        Bs[lk + 6][lr] = b2.z; Bs[lk + 7][lr] = b2.w;
        __syncthreads();
        #pragma unroll
        for (int kk = 0; kk < 16; kk++) {
            float4 av1 = *(const float4*)&As[kk][ty * 8];
            float4 av2 = *(const float4*)&As[kk][ty * 8 + 4];
            float4 bv1 = *(const float4*)&Bs[kk][tx * 8];
            float4 bv2 = *(const float4*)&Bs[kk][tx * 8 + 4];
            float am[8] = {av1.x, av1.y, av1.z, av1.w, av2.x, av2.y, av2.z, av2.w};
            float bn[8] = {bv1.x, bv1.y, bv1.z, bv1.w, bv2.x, bv2.y, bv2.z, bv2.w};
            #pragma unroll
            for (int i = 0; i < 8; i++)
                #pragma unroll
                for (int j = 0; j < 8; j++)
                    acc[i][j] += am[i] * bn[j];
        }
        __syncthreads();
    }

    int nc = n0 + tx * 8;
    float bb[8];
    #pragma unroll
    for (int j = 0; j < 8; j++) {
        bb[j] = 0.f;
        if (bias0) bb[j] += bias0[nc + j];
        if (bias1) bb[j] += bias1[nc + j];
    }
    #pragma unroll
    for (int i = 0; i < 8; i++) {
        int row = m0 + ty * 8 + i;
        float4 o1 = make_float4(acc[i][0] + bb[0], acc[i][1] + bb[1],
                                acc[i][2] + bb[2], acc[i][3] + bb[3]);
        float4 o2 = make_float4(acc[i][4] + bb[4], acc[i][5] + bb[5],
                                acc[i][6] + bb[6], acc[i][7] + bb[7]);
        *(float4*)(C + (size_t)row * N + nc) = o1;
        *(float4*)(C + (size_t)row * N + nc + 4) = o2;
    }
}

// ---------------------------------------------------------------------------
// NN SGEMM: C[m,n] = sum_k A[m*K+k]*B[k*N+n]  (for encT = enc_out @ attn_W)
// ---------------------------------------------------------------------------
__global__ __launch_bounds__(256) void gemm_nn128(const float* __restrict__ A,
                                                  const float* __restrict__ Bm,
                                                  float* __restrict__ C,
                                                  int M, int N, int K)
{
    __shared__ float As[16][128];
    __shared__ float Bs[16][128];
    int tid = threadIdx.x;
    int tx = tid & 15, ty = tid >> 4;
    int m0 = blockIdx.y * 128, n0 = blockIdx.x * 128;

    float acc[8][8];
    #pragma unroll
    for (int i = 0; i < 8; i++)
        #pragma unroll
        for (int j = 0; j < 8; j++) acc[i][j] = 0.f;

    int lr = tid >> 1, lk = (tid & 1) * 8;
    const float* Aptr = A + (size_t)(m0 + lr) * K + lk;
    int bk = tid >> 5;                // 0..7
    int bn = (tid & 31) << 2;         // 0..124

    for (int k0 = 0; k0 < K; k0 += 16) {
        float4 a1 = *(const float4*)(Aptr + k0);
        float4 a2 = *(const float4*)(Aptr + k0 + 4);
        float4 v1 = *(const float4*)(Bm + (size_t)(k0 + bk) * N + n0 + bn);
        float4 v2 = *(const float4*)(Bm + (size_t)(k0 + bk + 8) * N + n0 + bn);
        As[lk + 0][lr] = a1.x; As[lk + 1][lr] = a1.y;
        As[lk + 2][lr] = a1.z; As[lk + 3][lr] = a1.w;
        As[lk + 4][lr] = a2.x; As[lk + 5][lr] = a2.y;
        As[lk + 6][lr] = a2.z; As[lk + 7][lr] = a2.w;
        *(float4*)&Bs[bk][bn] = v1;
        *(float4*)&Bs[bk + 8][bn] = v2;
        __syncthreads();
        #pragma unroll
        for (int kk = 0; kk < 16; kk++) {
            float4 av1 = *(const float4*)&As[kk][ty * 8];
            float4 av2 = *(const float4*)&As[kk][ty * 8 + 4];
            float4 bv1 = *(const float4*)&Bs[kk][tx * 8];
            float4 bv2 = *(const float4*)&Bs[kk][tx * 8 + 4];
            float am[8] = {av1.x, av1.y, av1.z, av1.w, av2.x, av2.y, av2.z, av2.w};
            float bv[8] = {bv1.x, bv1.y, bv1.z, bv1.w, bv2.x, bv2.y, bv2.z, bv2.w};
            #pragma unroll
            for (int i = 0; i < 8; i++)
                #pragma unroll
                for (int j = 0; j < 8; j++)
                    acc[i][j] += am[i] * bv[j];
        }
        __syncthreads();
    }

    int nc = n0 + tx * 8;
    #pragma unroll
    for (int i = 0; i < 8; i++) {
        int row = m0 + ty * 8 + i;
        float4 o1 = make_float4(acc[i][0], acc[i][1], acc[i][2], acc[i][3]);
        float4 o2 = make_float4(acc[i][4], acc[i][5], acc[i][6], acc[i][7]);
        *(float4*)(C + (size_t)row * N + nc) = o1;
        *(float4*)(C + (size_t)row * N + nc + 4) = o2;
    }
}

// ---------------------------------------------------------------------------
// helpers
// ---------------------------------------------------------------------------
__device__ __forceinline__ float allreduce64(float v)
{
    #pragma unroll
    for (int m = 1; m < 64; m <<= 1) v += __shfl_xor(v, m);
    return v;
}

__device__ __forceinline__ float2 lstm_update(float i_, float f_, float g_,
                                              float o_, float c)
{
    float ig = 1.f / (1.f + expf(-i_));
    float fg = 1.f / (1.f + expf(-f_));
    float gg = tanhf(g_);
    float og = 1.f / (1.f + expf(-o_));
    float cn = fg * c + ig * gg;
    float hn = og * tanhf(cn);
    return make_float2(hn, cn);
}

// ---------------------------------------------------------------------------
// Fused 2-layer encoder, DATAFLOW-synced (no grid barriers).
// 128 L0 blocks + 128 L1 blocks; layer-1 trails layer-0 as a free-running
// pipeline. State X(t) lives in parity slot t&1.
// L0(t): waits F0>=t (h0(t-1) data, t>0) and F1>=t-1 (anti-overwrite, t>=2).
// L1(t): waits F0>=t+1 (h0(t) data) and F1>=t (h1(t-1) data, t>0).
// ---------------------------------------------------------------------------
__global__ __launch_bounds__(256) void enc_fused(
    const float* __restrict__ xg, const float* __restrict__ Whh0,
    const float* __restrict__ Wih1, const float* __restrict__ Whh1,
    const float* __restrict__ bih1, const float* __restrict__ bhh1,
    float* __restrict__ l1out, float* __restrict__ h0buf,
    float* __restrict__ h1buf, float* __restrict__ hT, float* __restrict__ cT,
    unsigned* __restrict__ flg)
{
    __shared__ __align__(16) float hs[16][520];
    __shared__ __align__(16) float is_[16][520];
    __shared__ float gacc[8][16][5];
    unsigned* F0 = flg;
    unsigned* F1 = flg + 2048;
    int blk = blockIdx.x;
    int xcd = blk & 7, slot = blk >> 3;
    int role = slot >> 4;
    int s2 = slot & 15;
    int jgroup = xcd * 8 + (s2 >> 1);        // [0,64)
    int bg2 = s2 & 1;
    int tid = threadIdx.x;
    int r = tid >> 3, bb = tid & 7;
    int g = r >> 3, jj = r & 7;
    int row = (g << 9) + (jgroup << 3) + jj; // gate-row in [0,2048)
    int b0 = (bg2 << 4) + bb;
    unsigned* myflag = (role ? F1 : F0) + (((jgroup << 1) + bg2) << 4);
    float creg = 0.f;

    if (!role) {
        // ---------------- layer 0 ----------------
        const float* w0 = Whh0 + (size_t)row * 512;
        for (int t = 0; t < SENC; ++t) {
            int ws = t & 1, rs = ws ^ 1;
            if (t > 0 && tid < 64)
                pollge(F0 + (((tid << 1) + bg2) << 4), (unsigned)t);
            else if (t >= 2 && tid >= 64 && tid < 128)
                pollge(F1 + ((((tid - 64) << 1) + bg2) << 4), (unsigned)(t - 1));
            __syncthreads();
            // stage h0(t-1)
            if (t == 0) {
                float4 z = make_float4(0.f, 0.f, 0.f, 0.f);
                #pragma unroll
                for (int v = 0; v < 8; v++) {
                    int d = (tid + (v << 8)) << 2;
                    *(float4*)&hs[d >> 9][d & 511] = z;
                }
            } else {
                const float4* s4 = (const float4*)(h0buf + rs * BH + ((bg2 << 4) << 9));
                float4 hv[8];
                #pragma unroll
                for (int v = 0; v < 8; v++)
                    hv[v] = agent_ld4((const float*)(s4 + tid + (v << 8)));
                asm volatile("s_waitcnt vmcnt(0)" ::: "memory");
                #pragma unroll
                for (int v = 0; v < 8; v++) {
                    int d = (tid + (v << 8)) << 2;
                    *(float4*)&hs[d >> 9][d & 511] = hv[v];
                }
            }
            __syncthreads();
            float acc0 = xg[(size_t)(b0 * SENC + t) * G4 + row];
            float acc1 = xg[(size_t)((b0 + 8) * SENC + t) * G4 + row];
            {
                float a00 = 0, a01 = 0, a02 = 0, a03 = 0;
                float a10 = 0, a11 = 0, a12 = 0, a13 = 0;
                const float* ha = hs[bb];
                const float* hb = hs[bb + 8];
                #pragma unroll 4
                for (int k = 0; k < 512; k += 4) {
                    float4 w = *(const float4*)(w0 + k);
                    float4 x = *(const float4*)(ha + k);
                    float4 y = *(const float4*)(hb + k);
                    a00 += w.x * x.x; a01 += w.y * x.y;
                    a02 += w.z * x.z; a03 += w.w * x.w;
                    a10 += w.x * y.x; a11 += w.y * y.y;
                    a12 += w.z * y.z; a13 += w.w * y.w;
                }
                acc0 += (a00 + a01) + (a02 + a03);
                acc1 += (a10 + a11) + (a12 + a13);
            }
            gacc[jj][bb][g] = acc0;
            gacc[jj][bb + 8][g] = acc1;
            __syncthreads();
            if (tid < 128) {
                int ujj = tid & 7, ulb = tid >> 3;
                float g0 = gacc[ujj][ulb][0], g1 = gacc[ujj][ulb][1];
                float g2 = gacc[ujj][ulb][2], g3 = gacc[ujj][ulb][3];
                float2 hc = lstm_update(g0, g1, g2, g3, creg);
                creg = hc.y;
                int ub = (bg2 << 4) + ulb;
                int ujh = (jgroup << 3) + ujj;
                agent_st(h0buf + ws * BH + ub * 512 + ujh, hc.x);
                if (t == SENC - 1) {
                    hT[ub * 512 + ujh] = hc.x;
                    cT[ub * 512 + ujh] = hc.y;
                }
            }
            flag_release(myflag, (unsigned)(t + 1));
        }
    } else {
        // ---------------- layer 1 ----------------
        const float* w0 = Wih1 + (size_t)row * 512;
        const float* w1 = Whh1 + (size_t)row * 512;
        float bsum = bih1[row] + bhh1[row];
        for (int t = 0; t < SENC; ++t) {
            int ws = t & 1, rs = ws ^ 1;
            if (tid < 64)
                pollge(F0 + (((tid << 1) + bg2) << 4), (unsigned)(t + 1));
            else if (t > 0 && tid < 128)
                pollge(F1 + ((((tid - 64) << 1) + bg2) << 4), (unsigned)t);
            __syncthreads();
            // stage h0(t) [slot ws] and h1(t-1) [slot rs]
            {
                const float4* s40 = (const float4*)(h0buf + ws * BH + ((bg2 << 4) << 9));
                float4 hv[8];
                #pragma unroll
                for (int v = 0; v < 8; v++)
                    hv[v] = agent_ld4((const float*)(s40 + tid + (v << 8)));
                if (t == 0) {
                    asm volatile("s_waitcnt vmcnt(0)" ::: "memory");
                    float4 z = make_float4(0.f, 0.f, 0.f, 0.f);
                    #pragma unroll
                    for (int v = 0; v < 8; v++) {
                        int d = (tid + (v << 8)) << 2;
                        *(float4*)&hs[d >> 9][d & 511] = hv[v];
                        *(float4*)&is_[d >> 9][d & 511] = z;
                    }
                } else {
                    const float4* s41 = (const float4*)(h1buf + rs * BH + ((bg2 << 4) << 9));
                    float4 iv[8];
                    #pragma unroll
                    for (int v = 0; v < 8; v++)
                        iv[v] = agent_ld4((const float*)(s41 + tid + (v << 8)));
                    asm volatile("s_waitcnt vmcnt(0)" ::: "memory");
                    #pragma unroll
                    for (int v = 0; v < 8; v++) {
                        int d = (tid + (v << 8)) << 2;
                        *(float4*)&hs[d >> 9][d & 511] = hv[v];
                        *(float4*)&is_[d >> 9][d & 511] = iv[v];
                    }
                }
            }
            __syncthreads();
            float acc0, acc1;
            {
                float a00 = 0, a01 = 0, a02 = 0, a03 = 0;
                float a10 = 0, a11 = 0, a12 = 0, a13 = 0;
                const float* h0a = hs[bb];
                const float* h0b = hs[bb + 8];
                const float* h1a = is_[bb];
                const float* h1b = is_[bb + 8];
                #pragma unroll 2
                for (int k = 0; k < 512; k += 4) {
                    float4 wi = *(const float4*)(w0 + k);
                    float4 wh = *(const float4*)(w1 + k);
                    float4 xa = *(const float4*)(h0a + k);
                    float4 xb = *(const float4*)(h0b + k);
                    float4 ya = *(const float4*)(h1a + k);
                    float4 yb = *(const float4*)(h1b + k);
                    a00 += wi.x * xa.x + wh.x * ya.x;
                    a01 += wi.y * xa.y + wh.y * ya.y;
                    a02 += wi.z * xa.z + wh.z * ya.z;
                    a03 += wi.w * xa.w + wh.w * ya.w;
                    a10 += wi.x * xb.x + wh.x * yb.x;
                    a11 += wi.y * xb.y + wh.y * yb.y;
                    a12 += wi.z * xb.z + wh.z * yb.z;
                    a13 += wi.w * xb.w + wh.w * yb.w;
                }
                acc0 = bsum + (a00 + a01) + (a02 + a03);
                acc1 = bsum + (a10 + a11) + (a12 + a13);
            }
            gacc[jj][bb][g] = acc0;
            gacc[jj][bb + 8][g] = acc1;
            __syncthreads();
            if (tid < 128) {
                int ujj = tid & 7, ulb = tid >> 3;
                float g0 = gacc[ujj][ulb][0], g1 = gacc[ujj][ulb][1];
                float g2 = gacc[ujj][ulb][2], g3 = gacc[ujj][ulb][3];
                float2 hc = lstm_update(g0, g1, g2, g3, creg);
                creg = hc.y;
                int ub = (bg2 << 4) + ulb;
                int ujh = (jgroup << 3) + ujj;
                agent_st(h1buf + ws * BH + ub * 512 + ujh, hc.x);
                l1out[(size_t)(ub * SENC + t) * 512 + ujh] = hc.x;
                if (t == SENC - 1) {
                    hT[BH + ub * 512 + ujh] = hc.x;
                    cT[BH + ub * 512 + ujh] = hc.y;
                }
            }
            flag_release(myflag, (unsigned)(t + 1));
        }
    }
}

// ---------------------------------------------------------------------------
// Decoder LSTM cell phase (device fn). Coherent x4 staging; L2 weights.
// ---------------------------------------------------------------------------
__device__ __forceinline__ void cell_phase(
    const float* __restrict__ Wih, const float* __restrict__ Whh,
    float bsum,
    const float* __restrict__ inp, const float* __restrict__ h_in,
    float* __restrict__ h_out, float* __restrict__ seqout,
    float& creg, int t, int jg, int bg, int row,
    float (*hs)[520], float (*is_)[520], float (*gacc)[8][5])
{
    int tid = threadIdx.x;
    {
        const float4* hsrc4 = (const float4*)(h_in + ((bg << 3) << 9));
        const float4* isrc4 = (const float4*)(inp + ((bg << 3) << 9));
        float4 hv4[4], iv4[4];
        #pragma unroll
        for (int u = 0; u < 4; u++) {
            hv4[u] = agent_ld4((const float*)(hsrc4 + tid + (u << 8)));
            iv4[u] = agent_ld4((const float*)(isrc4 + tid + (u << 8)));
        }
        asm volatile("s_waitcnt vmcnt(0)" ::: "memory");
        #pragma unroll
        for (int u = 0; u < 4; u++) {
            int d = (tid + (u << 8)) << 2;
            int rb = d >> 9, kk = d & 511;
            *(float4*)&hs[rb][kk] = hv4[u];
            *(float4*)&is_[rb][kk] = iv4[u];
        }
    }
    __syncthreads();
    int r = tid >> 3, bb = tid & 7;
    int g = r >> 3, jj = r & 7;
    const float* wi = Wih + (size_t)row * 512;
    const float* wh = Whh + (size_t)row * 512;
    const float* ir = is_[bb];
    const float* hr = hs[bb];
    float a0 = 0.f, a1 = 0.f, a2 = 0.f, a3 = 0.f;
    #pragma unroll 8
    for (int k = 0; k < 512; k += 4) {
        float4 wiv = *(const float4*)(wi + k);
        float4 iv = *(const float4*)(ir + k);
        float4 whv = *(const float4*)(wh + k);
        float4 hv = *(const float4*)(hr + k);
        a0 += wiv.x * iv.x + whv.x * hv.x;
        a1 += wiv.y * iv.y + whv.y * hv.y;
        a2 += wiv.z * iv.z + whv.z * hv.z;
        a3 += wiv.w * iv.w + whv.w * hv.w;
    }
    gacc[jj][bb][g] = bsum + (a0 + a1) + (a2 + a3);
    __syncthreads();
    if (tid < 64) {
        int ujj = tid & 7, ubb = tid >> 3;
        float g0 = gacc[ujj][ubb][0], g1 = gacc[ujj][ubb][1];
        float g2 = gacc[ujj][ubb][2], g3 = gacc[ujj][ubb][3];
        float2 hc = lstm_update(g0, g1, g2, g3, creg);
        creg = hc.y;
        int ub = (bg << 3) + ubb, ujh = (jg << 3) + ujj;
        agent_st(h_out + ub * 512 + ujh, hc.x);
        if (seqout) seqout[(size_t)(ub * SDEC + t) * 512 + ujh] = hc.x;
    }
}

// ---------------------------------------------------------------------------
// Persistent decoder, DATAFLOW-synced: per-step chain A -> B -> C where each
// consumer wave-polls only its 64 producers' flags (~1 coherence round-trip)
// instead of a global barrier (~5 round-trips). Parity slot = t&1.
//  A(t): needs h2(t-1) -> FC[*,abg] >= t (skip t=0: hT1)
//  B(t): needs inp(t)  -> FA[bg*64+*] >= t+1 ; h0(t-1) -> FB[*,bg] >= t
//  C(t): needs h0(t)   -> FB[*,bg] >= t+1   ; h1(t-1) -> FC[*,bg] >= t
// Buffer-overwrite safety follows transitively from these waits (2-slot
// parity, in-order blocks) -- verified for dhb0/dhb1/inpbuf.
// ---------------------------------------------------------------------------
__global__ __launch_bounds__(256) void decoder_persist(
    const int* __restrict__ xs,
    const float* __restrict__ encT, const float* __restrict__ encC,
    const float* __restrict__ yg,
    const float* __restrict__ Wih0, const float* __restrict__ Whh0,
    const float* __restrict__ bih0, const float* __restrict__ bhh0,
    const float* __restrict__ Wih1, const float* __restrict__ Whh1,
    const float* __restrict__ bih1, const float* __restrict__ bhh1,
    const float* __restrict__ hT0, const float* __restrict__ cT0,
    const float* __restrict__ hT1, const float* __restrict__ cT1,
    float* __restrict__ dhb0, float* __restrict__ dhb1,
    float* __restrict__ inpbuf, float* __restrict__ h2seq,
    unsigned* __restrict__ flg)
{
    __shared__ __align__(16) float hs[8][520];
    __shared__ __align__(16) float is_[8][520];
    __shared__ float gacc[8][8][5];
    __shared__ __align__(16) float h2s[512];
    __shared__ float psum[4][64];
    __shared__ float pw[64];
    __shared__ float aw[64];
    unsigned* FA = flg + 4096;
    unsigned* FB = flg + 8192;
    unsigned* FC = flg + 12288;
    int blk = blockIdx.x;
    int xcd = blk & 7, slot = blk >> 3;
    int jg = xcd * 8 + (slot >> 2), bg = slot & 3;    // cell role
    int ab = xcd * 4 + (slot >> 3);                   // attention b (XCD-pinned)
    int esl = slot & 7;                               // attention e-slice idx
    int e0 = esl << 6;
    int abg = ab >> 3;                                // bg-range containing ab
    int tid = threadIdx.x;
    int lane = tid & 63, wv = tid >> 6;
    int r = tid >> 3;
    int g = r >> 3, jj = r & 7;
    int row = (g << 9) + (jg << 3) + jj;
    float bsum0 = bih0[row] + bhh0[row];
    float bsum1 = bih1[row] + bhh1[row];
    unsigned* flagA = FA + (((ab << 3) + esl) << 4);
    unsigned* flagB = FB + (((jg << 2) + bg) << 4);
    unsigned* flagC = FC + (((jg << 2) + bg) << 4);
    float c0 = 0.f, c1 = 0.f;
    if (tid < 64) {
        int ujj = tid & 7, ubb = tid >> 3;
        int ub = (bg << 3) + ubb, ujh = (jg << 3) + ujj;
        c0 = cT0[ub * 512 + ujh];
        c1 = cT1[ub * 512 + ujh];
    }
    for (int t = 0; t < SDEC; ++t) {
        int ws = t & 1, rs = ws ^ 1;
        // ---- Phase A: attention + combine ----
        if (t > 0 && tid < 64)
            pollge(FC + (((tid << 2) + abg) << 4), (unsigned)t);
        __syncthreads();
        {
            const float* h2p = ((t == 0) ? hT1 : dhb1 + rs * BH) + ab * 512;
            if (tid < 128) {
                float4 v = agent_ld4((const float*)((const float4*)h2p + tid));
                asm volatile("s_waitcnt vmcnt(0)" ::: "memory");
                ((float4*)h2s)[tid] = v;
            }
            __syncthreads();
            // pw[s] = h2 . encT[ab,s] - neg (redundant across e-slice blocks)
            for (int s = wv; s < SENC; s += 4) {
                const float* rowp = encT + (size_t)(ab * SENC + s) * 512;
                float pp = 0.f;
                #pragma unroll
                for (int i = 0; i < 8; i++)
                    pp += h2s[lane + 64 * i] * rowp[lane + 64 * i];
                pp = allreduce64(pp);
                if (lane == 0)
                    pw[s] = pp - ((xs[ab * SENC + s] > 0) ? 0.f : 1e20f);
            }
            __syncthreads();
            if (tid < 64) {
                float v = pw[tid];
                float m = v;
                #pragma unroll
                for (int o = 1; o < 64; o <<= 1) m = fmaxf(m, __shfl_xor(m, o));
                float ex = expf(v - m);
                float sm = ex;
                #pragma unroll
                for (int o = 1; o < 64; o <<= 1) sm += __shfl_xor(sm, o);
                aw[tid] = ex / sm;
            }
            __syncthreads();
            // inp[e0+lane] = tanh(yg + sum_s aw[s]*encC[ab,s,e0+lane])
            {
                float part = 0.f;
                const float* cb = encC + (size_t)(ab * SENC + (wv << 4)) * 512
                                + e0 + lane;
                #pragma unroll
                for (int si = 0; si < 16; si++)
                    part += aw[(wv << 4) + si] * cb[si * 512];
                psum[wv][lane] = part;
            }
            __syncthreads();
            if (tid < 64) {
                float v = psum[0][tid] + psum[1][tid] + psum[2][tid] + psum[3][tid];
                float rr = tanhf(yg[(size_t)(ab * SDEC + t) * 512 + e0 + tid] + v);
                agent_st(inpbuf + ab * 512 + e0 + tid, rr);
            }
        }
        flag_release(flagA, (unsigned)(t + 1));
        // ---- Phase B: layer-0 cell ----
        if (tid < 64)
            pollge(FA + (((bg << 6) + tid) << 4), (unsigned)(t + 1));
        else if (t > 0 && tid < 128)
            pollge(FB + ((((tid - 64) << 2) + bg) << 4), (unsigned)t);
        __syncthreads();
        cell_phase(Wih0, Whh0, bsum0, inpbuf,
                   (t == 0) ? hT0 : dhb0 + rs * BH, dhb0 + ws * BH,
                   (float*)nullptr, c0, t, jg, bg, row, hs, is_, gacc);
        flag_release(flagB, (unsigned)(t + 1));
        // ---- Phase C: layer-1 cell ----
        if (tid < 64)
            pollge(FB + (((tid << 2) + bg) << 4), (unsigned)(t + 1));
        else if (t > 0 && tid < 128)
            pollge(FC + ((((tid - 64) << 2) + bg) << 4), (unsigned)t);
        __syncthreads();
        cell_phase(Wih1, Whh1, bsum1, dhb0 + ws * BH,
                   (t == 0) ? hT1 : dhb1 + rs * BH, dhb1 + ws * BH,
                   h2seq, c1, t, jg, bg, row, hs, is_, gacc);
        flag_release(flagC, (unsigned)(t + 1));
    }
}

// ---------------------------------------------------------------------------
// argmax over scores[m, 1:], lowest index on ties; preds[m] = index (float)
// ---------------------------------------------------------------------------
__global__ __launch_bounds__(256) void argmax_kernel(const float* __restrict__ scores,
                                                     float* __restrict__ preds)
{
    __shared__ float sv[256];
    __shared__ int si[256];
    int m = blockIdx.x;
    const float* row = scores + (size_t)m * VDIM;
    float best = -3.4e38f;
    int bi = 0x7fffffff;
    for (int v = 1 + (int)threadIdx.x; v < VDIM; v += 256) {
        float val = row[v];
        if (val > best) { best = val; bi = v; }   // ascending scan → lowest idx kept
    }
    sv[threadIdx.x] = best;
    si[threadIdx.x] = bi;
    __syncthreads();
    for (int s = 128; s > 0; s >>= 1) {
        if ((int)threadIdx.x < s) {
            float ov = sv[threadIdx.x + s];
            int oi = si[threadIdx.x + s];
            if (ov > sv[threadIdx.x] ||
                (ov == sv[threadIdx.x] && oi < si[threadIdx.x])) {
                sv[threadIdx.x] = ov;
                si[threadIdx.x] = oi;
            }
        }
        __syncthreads();
    }
    if (threadIdx.x == 0) preds[m] = (float)si[0];
}

// ---------------------------------------------------------------------------
extern "C" void kernel_launch(void* const* d_in, const int* in_sizes, int n_in,
                              void* d_out, int out_size, void* d_ws, size_t ws_size,
                              hipStream_t stream)
{
    const int* xs = (const int*)d_in[0];
    const int* ys = (const int*)d_in[1];
    const float* emb = (const float*)d_in[2];
    const float* W[16];
    for (int i = 0; i < 16; i++) W[i] = (const float*)d_in[3 + i];
    // enc layer l: W[l*4+{0:Wih,1:Whh,2:bih,3:bhh}] ; dec layer l: W[8+l*4+...]
    const float* attn_W = (const float*)d_in[19];
    const float* comb_W = (const float*)d_in[20];
    float* out = (float*)d_out;
    float* ws = (float*)d_ws;

    // workspace layout (floats)
    float* xemb   = ws;                    // 2048*512
    float* xg     = xemb + 1048576;        // 2048*2048 (layer-0 pre-gates)
    float* l1out  = xg + 4194304;          // 2048*512  (enc_out)
    float* encT   = l1out + 1048576;       // 2048*512  (enc_out @ attn_W)
    float* h0buf  = encT + 1048576;        // 2*BH
    float* h1buf  = h0buf + 2 * BH;        // 2*BH
    float* hT     = h1buf + 2 * BH;        // 2*BH (layer0 | layer1)
    float* cT     = hT + 2 * BH;           // 2*BH
    unsigned* flg = (unsigned*)(cT + 2 * BH);      // 16384 dwords (flags)
    // ys embeddings overlay xemb (dead after layer-0 pre-gate GEMM)
    float* yemb   = xemb;                  // 1024*512
    // decoder buffers overlay xg (dead after encoder)
    float* h2seq  = xg;                    // 1024*512
    float* inpbuf = xg + 524288;           // BH
    float* dhb0   = inpbuf + BH;           // 2*BH parity
    float* dhb1   = dhb0 + 2 * BH;         // 2*BH parity
    float* yg     = dhb1 + 2 * BH;         // 1024*512 (yemb @ Wxe^T)
    float* encC   = yg + 524288;           // 2048*512 (enc_out @ Wc^T)

    hipMemsetAsync(flg, 0, FLG_BYTES, stream);

    // ---- Encoder ----
    embed_kernel<<<B * SENC, 128, 0, stream>>>(xs, emb, xemb);
    gemm_nt128<<<dim3(G4 / 128, (B * SENC) / 128), 256, 0, stream>>>(
        xemb, W[0], xg, W[2], W[3], B * SENC, G4, 512, 512);
    embed_kernel<<<B * SDEC, 128, 0, stream>>>(ys, emb, yemb);
    {
        const float* xgp = xg;
        const float* whh0 = W[1];
        const float* wih1 = W[4];
        const float* whh1 = W[5];
        const float* bih1 = W[6];
        const float* bhh1 = W[7];
        float* l1o = l1out;
        float* h0b = h0buf;
        float* h1b = h1buf;
        float* hTp = hT;
        float* cTp = cT;
        unsigned* fp = flg;
        void* eargs[] = {(void*)&xgp, (void*)&whh0, (void*)&wih1, (void*)&whh1,
                         (void*)&bih1, (void*)&bhh1, (void*)&l1o, (void*)&h0b,
                         (void*)&h1b, (void*)&hTp, (void*)&cTp, (void*)&fp};
        hipLaunchCooperativeKernel((void*)enc_fused, dim3(NBLK), dim3(256),
                                   eargs, 0, stream);
    }

    // ---- Attention precomputes (off the recurrence) ----
    gemm_nn128<<<dim3(512 / 128, (B * SENC) / 128), 256, 0, stream>>>(
        l1out, attn_W, encT, B * SENC, 512, 512);
    gemm_nt128<<<dim3(512 / 128, (B * SDEC) / 128), 256, 0, stream>>>(
        yemb, comb_W, yg, nullptr, nullptr, B * SDEC, 512, 512, 1024);
    gemm_nt128<<<dim3(512 / 128, (B * SENC) / 128), 256, 0, stream>>>(
        l1out, comb_W + 512, encC, nullptr, nullptr, B * SENC, 512, 512, 1024);

    // ---- Decoder (single persistent kernel, dataflow-synced) ----
    {
        const int* xs_ = xs;
        const float* encT_ = encT;
        const float* encC_ = encC;
        const float* yg_ = yg;
        const float* wih0 = W[8];
        const float* whh0 = W[9];
        const float* bih0 = W[10];
        const float* bhh0 = W[11];
        const float* wih1 = W[12];
        const float* whh1 = W[13];
        const float* bih1 = W[14];
        const float* bhh1 = W[15];
        const float* hT0_ = hT;
        const float* cT0_ = cT;
        const float* hT1_ = hT + BH;
        const float* cT1_ = cT + BH;
        float* dhb0_ = dhb0;
        float* dhb1_ = dhb1;
        float* inp_ = inpbuf;
        float* h2seq_ = h2seq;
        unsigned* fp = flg;
        void* dargs[] = {(void*)&xs_, (void*)&encT_, (void*)&encC_,
                         (void*)&yg_,
                         (void*)&wih0, (void*)&whh0, (void*)&bih0, (void*)&bhh0,
                         (void*)&wih1, (void*)&whh1, (void*)&bih1, (void*)&bhh1,
                         (void*)&hT0_, (void*)&cT0_, (void*)&hT1_, (void*)&cT1_,
                         (void*)&dhb0_, (void*)&dhb1_, (void*)&inp_, (void*)&h2seq_,
                         (void*)&fp};
        hipLaunchCooperativeKernel((void*)decoder_persist, dim3(NBLK), dim3(256),
                                   dargs, 0, stream);
    }

    // ---- Output projection + argmax ----
    gemm_nt128<<<dim3(VDIM / 128, (B * SDEC) / 128), 256, 0, stream>>>(
        h2seq, emb, out + B * SDEC, nullptr, nullptr, B * SDEC, VDIM, 512, 512);
    argmax_kernel<<<B * SDEC, 256, 0, stream>>>(out + B * SDEC, out);
}